// Round 2
// baseline (1109.475 us; speedup 1.0000x reference)
//
#include <hip/hip_runtime.h>

#define B_ 2
#define I_ 2048
#define M_ 2048
#define D_ 1024
#define H_ 16
#define Dh_ 64
// S row stride = 2048 floats exactly; bank spread via XOR swizzle of col bits 2..4 by row
// (T2: lanes read different rows at same col-range -> without swizzle 8-way conflict)
#define SWZ(r, c) ((c) ^ (((r) & 7) << 2))

typedef __bf16 bf16_t;
typedef __bf16 bf16x8 __attribute__((ext_vector_type(8)));
typedef __bf16 bf16x4 __attribute__((ext_vector_type(4)));
typedef float f32x4 __attribute__((ext_vector_type(4)));

// float -> bf16 round-to-nearest-even (manual, avoids relying on fptrunc semantics)
__device__ __forceinline__ bf16_t f2b(float f) {
    union { float f; unsigned u; } in;
    in.f = f;
    unsigned r = (in.u + 0x7fffu + ((in.u >> 16) & 1u)) >> 16;
    union { unsigned short s; bf16_t b; } out;
    out.s = (unsigned short)r;
    return out.b;
}

// hw packed f32->bf16 RNE (no builtin on gfx950; T12 primitive)
__device__ __forceinline__ unsigned cvt_pk_bf16(float lo, float hi) {
    unsigned r;
    asm("v_cvt_pk_bf16_f32 %0, %1, %2" : "=v"(r) : "v"(lo), "v"(hi));
    return r;
}

// ---------------- cast fp32 -> bf16 (vectorized) ----------------
__global__ void cast_f32_bf16(const float* __restrict__ src, bf16_t* __restrict__ dst, int n) {
    int idx = (blockIdx.x * blockDim.x + threadIdx.x) * 4;
    if (idx + 3 < n) {
        float4 v = *(const float4*)(src + idx);
        bf16x4 o;
        o[0] = f2b(v.x); o[1] = f2b(v.y); o[2] = f2b(v.z); o[3] = f2b(v.w);
        *(bf16x4*)(dst + idx) = o;
    }
}

// ---------------- transpose 1024x1024 fp32 -> bf16 (Wt[n][k] = W[k][n]) ----------------
__global__ void transpose_cast(const float* __restrict__ src, bf16_t* __restrict__ dst) {
    __shared__ float tile[32][33];
    int n0 = blockIdx.x * 32, k0 = blockIdx.y * 32;
    int tx = threadIdx.x, ty = threadIdx.y;  // 32 x 8
#pragma unroll
    for (int i = 0; i < 4; i++)
        tile[ty + i * 8][tx] = src[(size_t)(k0 + ty + i * 8) * D_ + n0 + tx];
    __syncthreads();
#pragma unroll
    for (int i = 0; i < 4; i++)
        dst[(size_t)(n0 + ty + i * 8) * D_ + k0 + tx] = f2b(tile[tx][ty + i * 8]);
}

// ---------------- NT GEMM: C[m][n] = sum_k A[m][k] * Bt[n][k]  (128x128 tile) ----------
// MODE 0: bf16 row-major out [RM x 1024], scaled
// MODE 1: bf16 out written as Vt[((b*16+h)*64+d)*2048 + m], via LDS-transpose epilogue
// MODE 2: fp32 row-major out
template <int MODE>
__global__ __launch_bounds__(256) void gemm_nt(const bf16_t* __restrict__ A,
                                               const bf16_t* __restrict__ Bt,
                                               void* __restrict__ Cout, float scale) {
    constexpr int LDT = 40;  // 32 + 8 pad (keeps 16B alignment, spreads banks)
    __shared__ bf16_t As[128 * LDT];
    __shared__ bf16_t Bs[128 * LDT];
    int m0 = blockIdx.x * 128, n0 = blockIdx.y * 128;
    int tid = threadIdx.x;
    int wave = tid >> 6, lane = tid & 63, quad = lane >> 4, l16 = lane & 15;
    int wr = wave >> 1, wc = wave & 1;
    f32x4 acc[4][4] = {};

    for (int k0 = 0; k0 < D_; k0 += 32) {
        // stage A and Bt tiles: 128 rows x 32 k each, 16B chunks
#pragma unroll
        for (int c = tid; c < 512; c += 256) {
            int r = c >> 2, ko = (c & 3) * 8;
            *(bf16x8*)&As[r * LDT + ko] = *(const bf16x8*)&A[(size_t)(m0 + r) * D_ + k0 + ko];
            *(bf16x8*)&Bs[r * LDT + ko] = *(const bf16x8*)&Bt[(size_t)(n0 + r) * D_ + k0 + ko];
        }
        __syncthreads();
        bf16x8 af[4], bfr[4];
#pragma unroll
        for (int i = 0; i < 4; i++) af[i] = *(bf16x8*)&As[(wr * 64 + i * 16 + l16) * LDT + quad * 8];
#pragma unroll
        for (int j = 0; j < 4; j++) bfr[j] = *(bf16x8*)&Bs[(wc * 64 + j * 16 + l16) * LDT + quad * 8];
#pragma unroll
        for (int i = 0; i < 4; i++)
#pragma unroll
            for (int j = 0; j < 4; j++)
                acc[i][j] = __builtin_amdgcn_mfma_f32_16x16x32_bf16(af[i], bfr[j], acc[i][j], 0, 0, 0);
        __syncthreads();
    }

    if (MODE == 1) {
        // Vt epilogue: direct scatter would be 2B/lane at 4KB stride (64 lines per store).
        // Instead stage 32-col strips (128m x 32n) in LDS, write 256B-contiguous runs.
        bf16_t* Ts = As;  // reuse staging LDS: 32*136*2 = 8704 B <= 10240 B
#pragma unroll
        for (int s = 0; s < 4; s++) {
            __syncthreads();
            if (wc == (s >> 1)) {
#pragma unroll
                for (int jj = 0; jj < 2; jj++) {
                    int j = (s & 1) * 2 + jj;
#pragma unroll
                    for (int i = 0; i < 4; i++)
#pragma unroll
                        for (int r = 0; r < 4; r++)
                            Ts[(jj * 16 + l16) * 136 + wr * 64 + i * 16 + quad * 4 + r] =
                                f2b(acc[i][j][r] * scale);
                }
            }
            __syncthreads();
#pragma unroll
            for (int it = 0; it < 2; it++) {
                int task = it * 256 + tid;
                int ns = task >> 4, ch = task & 15;
                int n = n0 + s * 32 + ns;
                int m = m0 + ch * 8;
                int bb = m >> 11, mm = m & 2047, hh = n >> 6, d = n & 63;
                *(bf16x8*)&((bf16_t*)Cout)[(((size_t)(bb * H_ + hh) * Dh_ + d) << 11) + mm] =
                    *(bf16x8*)&Ts[ns * 136 + ch * 8];
            }
        }
        return;
    }

#pragma unroll
    for (int i = 0; i < 4; i++)
#pragma unroll
        for (int j = 0; j < 4; j++) {
            int n = n0 + wc * 64 + j * 16 + l16;
#pragma unroll
            for (int r = 0; r < 4; r++) {
                int m = m0 + wr * 64 + i * 16 + quad * 4 + r;
                float v = acc[i][j][r] * scale;
                if (MODE == 0) {
                    ((bf16_t*)Cout)[(size_t)m * D_ + n] = f2b(v);
                } else {
                    ((float*)Cout)[(size_t)m * D_ + n] = v;
                }
            }
        }
}

// ---------------- fused attention: S=QK^T+bias, softmax, write align, PV --------------
// 1024 threads (16 waves) per block; 128 KiB LDS S tile -> 1 block/CU, 4 waves/SIMD.
__global__ __launch_bounds__(1024) void attn_fused(const bf16_t* __restrict__ Q,
                                                   const bf16_t* __restrict__ K,
                                                   const bf16_t* __restrict__ Vt,
                                                   const float* __restrict__ bias,
                                                   float* __restrict__ align_out,
                                                   bf16_t* __restrict__ AO) {
    extern __shared__ float S[];  // 16 rows x 2048 floats, XOR-swizzled cols
    __shared__ float rowinv[16];
    int i0 = blockIdx.x * 16, h = blockIdx.y, b = blockIdx.z;
    int tid = threadIdx.x, wave = tid >> 6, lane = tid & 63, quad = lane >> 4, l16 = lane & 15;

    // Q A-fragments (16 rows x Dh=64), shared by all waves
    size_t qrow = (size_t)(b * I_ + i0 + l16) * D_ + h * Dh_ + quad * 8;
    bf16x8 aq0 = *(const bf16x8*)&Q[qrow];
    bf16x8 aq1 = *(const bf16x8*)&Q[qrow + 32];

    // ---- QK^T: each wave does 8 consecutive m-tiles ----
#pragma unroll
    for (int t = 0; t < 8; t++) {
        int m0 = wave * 128 + t * 16;
        size_t krow = (size_t)(b * M_ + m0 + l16) * D_ + h * Dh_ + quad * 8;
        bf16x8 bk0 = *(const bf16x8*)&K[krow];
        bf16x8 bk1 = *(const bf16x8*)&K[krow + 32];
        f32x4 acc = {};
        acc = __builtin_amdgcn_mfma_f32_16x16x32_bf16(aq0, bk0, acc, 0, 0, 0);
        acc = __builtin_amdgcn_mfma_f32_16x16x32_bf16(aq1, bk1, acc, 0, 0, 0);
#pragma unroll
        for (int r = 0; r < 4; r++) {
            int i = quad * 4 + r;
            float v = acc[r] + bias[((size_t)b * I_ + i0 + i) * M_ + m0 + l16];
            S[i * 2048 + SWZ(i, m0 + l16)] = v;
        }
    }
    __syncthreads();

    // ---- softmax stats: one full wave per row, 64-lane shuffle reduce ----
    {
        int row = wave;
        float* srow = &S[row * 2048];
        float mx = -1e30f;
#pragma unroll
        for (int t = 0; t < 8; t++) {
            float4 v = *(float4*)&srow[SWZ(row, lane * 4 + t * 256)];
            mx = fmaxf(mx, fmaxf(fmaxf(v.x, v.y), fmaxf(v.z, v.w)));
        }
#pragma unroll
        for (int off = 1; off < 64; off <<= 1) mx = fmaxf(mx, __shfl_xor(mx, off));
        float sum = 0.f;
#pragma unroll
        for (int t = 0; t < 8; t++) {
            float4 v = *(float4*)&srow[SWZ(row, lane * 4 + t * 256)];
            v.x = __expf(v.x - mx); v.y = __expf(v.y - mx);
            v.z = __expf(v.z - mx); v.w = __expf(v.w - mx);
            *(float4*)&srow[SWZ(row, lane * 4 + t * 256)] = v;
            sum += v.x + v.y + v.z + v.w;
        }
#pragma unroll
        for (int off = 1; off < 64; off <<= 1) sum += __shfl_xor(sum, off);
        if (lane == 0) rowinv[row] = 1.0f / sum;
    }
    __syncthreads();

    // ---- write align block (16 x 2048 fp32, contiguous float4 stores) ----
    {
        float* dst = align_out + (((size_t)(b * H_ + h) * I_ + i0) << 11);
        for (int idx = tid; idx < 16 * 2048 / 4; idx += 1024) {
            int r = idx >> 9;
            int c = (idx & 511) * 4;
            float4 v = *(float4*)&S[r * 2048 + SWZ(r, c)];
            float iv = rowinv[r];
            v.x *= iv; v.y *= iv; v.z *= iv; v.w *= iv;
            *(float4*)&dst[((size_t)r << 11) + c] = v;
        }
    }

    // ---- PV: wave = (ktgroup, colgroup); partial accumulate then LDS reduce ----
    {
        int cg = wave & 3, kg = wave >> 2;
        int n0 = cg * 16;
        f32x4 o0 = {}, o1 = {};
        const bf16_t* vrow = &Vt[((size_t)(b * H_ + h) * Dh_ + n0 + l16) << 11];
        const float* srow = &S[l16 * 2048];
#pragma unroll
        for (int t = 0; t < 8; t++) {
            int kt = kg * 512 + t * 64;
            int c0 = kt + quad * 8;
            float4 f0 = *(const float4*)&srow[SWZ(l16, c0)];
            float4 f1 = *(const float4*)&srow[SWZ(l16, c0 + 4)];
            float4 f2 = *(const float4*)&srow[SWZ(l16, c0 + 32)];
            float4 f3 = *(const float4*)&srow[SWZ(l16, c0 + 36)];
            union { bf16x8 v; unsigned u[4]; } a0, a1;
            a0.u[0] = cvt_pk_bf16(f0.x, f0.y); a0.u[1] = cvt_pk_bf16(f0.z, f0.w);
            a0.u[2] = cvt_pk_bf16(f1.x, f1.y); a0.u[3] = cvt_pk_bf16(f1.z, f1.w);
            a1.u[0] = cvt_pk_bf16(f2.x, f2.y); a1.u[1] = cvt_pk_bf16(f2.z, f2.w);
            a1.u[2] = cvt_pk_bf16(f3.x, f3.y); a1.u[3] = cvt_pk_bf16(f3.z, f3.w);
            bf16x8 v0 = *(const bf16x8*)&vrow[kt + quad * 8];
            bf16x8 v1 = *(const bf16x8*)&vrow[kt + 32 + quad * 8];
            o0 = __builtin_amdgcn_mfma_f32_16x16x32_bf16(a0.v, v0, o0, 0, 0, 0);
            o1 = __builtin_amdgcn_mfma_f32_16x16x32_bf16(a1.v, v1, o1, 0, 0, 0);
        }
        __syncthreads();  // all reads of S complete; safe to reuse S as scratch
        float* scr = &S[(size_t)wave * 512 + (size_t)lane * 8];
        *(f32x4*)scr = o0;
        *(f32x4*)(scr + 4) = o1;
        __syncthreads();
        if (kg == 0) {
#pragma unroll
            for (int w2 = 1; w2 < 4; w2++) {
                const float* p = &S[(size_t)(w2 * 4 + cg) * 512 + (size_t)lane * 8];
                f32x4 p0 = *(const f32x4*)p;
                f32x4 p1 = *(const f32x4*)(p + 4);
                o0 += p0;
                o1 += p1;
            }
#pragma unroll
            for (int r = 0; r < 4; r++) {
                int i = quad * 4 + r;
                float v = (o0[r] + o1[r]) * rowinv[i];
                AO[(size_t)(b * I_ + i0 + i) * D_ + h * Dh_ + n0 + l16] = f2b(v);
            }
        }
    }
}

extern "C" void kernel_launch(void* const* d_in, const int* in_sizes, int n_in,
                              void* d_out, int out_size, void* d_ws, size_t ws_size,
                              hipStream_t stream) {
    const float* input  = (const float*)d_in[0];
    const float* memory = (const float*)d_in[1];
    const float* bias   = (const float*)d_in[2];
    const float* Wq     = (const float*)d_in[3];
    const float* Wk     = (const float*)d_in[4];
    const float* Wv     = (const float*)d_in[5];
    const float* Wo     = (const float*)d_in[6];

    float* out   = (float*)d_out;
    float* align = out + (size_t)B_ * I_ * D_;

    char* ws = (char*)d_ws;
    const size_t nBID = (size_t)B_ * I_ * D_;   // 4,194,304
    const size_t nDD  = (size_t)D_ * D_;        // 1,048,576
    bf16_t* in_b  = (bf16_t*)ws; ws += nBID * 2;
    bf16_t* mem_b = (bf16_t*)ws; ws += nBID * 2;
    bf16_t* Wq_t  = (bf16_t*)ws; ws += nDD * 2;
    bf16_t* Wk_t  = (bf16_t*)ws; ws += nDD * 2;
    bf16_t* Wv_t  = (bf16_t*)ws; ws += nDD * 2;
    bf16_t* Wo_t  = (bf16_t*)ws; ws += nDD * 2;
    bf16_t* Qb    = (bf16_t*)ws; ws += nBID * 2;
    bf16_t* Kb    = (bf16_t*)ws; ws += nBID * 2;
    bf16_t* Vt    = (bf16_t*)ws; ws += nBID * 2;
    bf16_t* AO    = (bf16_t*)ws; ws += nBID * 2;

    // casts
    cast_f32_bf16<<<nBID / 1024, 256, 0, stream>>>(input, in_b, (int)nBID);
    cast_f32_bf16<<<nBID / 1024, 256, 0, stream>>>(memory, mem_b, (int)nBID);
    dim3 tb(32, 8), tg(32, 32);
    transpose_cast<<<tg, tb, 0, stream>>>(Wq, Wq_t);
    transpose_cast<<<tg, tb, 0, stream>>>(Wk, Wk_t);
    transpose_cast<<<tg, tb, 0, stream>>>(Wv, Wv_t);
    transpose_cast<<<tg, tb, 0, stream>>>(Wo, Wo_t);

    // projections: [4096,1024] @ [1024,1024]^T-layout
    dim3 gg(32, 8);
    gemm_nt<0><<<gg, 256, 0, stream>>>(in_b, Wq_t, Qb, 0.125f);   // Dh^-0.5 folded
    gemm_nt<0><<<gg, 256, 0, stream>>>(mem_b, Wk_t, Kb, 1.0f);
    gemm_nt<1><<<gg, 256, 0, stream>>>(mem_b, Wv_t, Vt, 1.0f);    // per-head transposed

    // fused attention: 1024 threads/block (16 waves), 128 KiB dynamic LDS
    attn_fused<<<dim3(I_ / 16, H_, B_), 1024, 16 * 2048 * 4, stream>>>(Qb, Kb, Vt, bias, align, AO);

    // output projection (fp32 out)
    gemm_nt<2><<<gg, 256, 0, stream>>>(AO, Wo_t, out, 1.0f);
}

// Round 3
// 1035.799 us; speedup vs baseline: 1.0711x; 1.0711x over previous
//
#include <hip/hip_runtime.h>

#define B_ 2
#define I_ 2048
#define M_ 2048
#define D_ 1024
#define H_ 16
#define Dh_ 64
// attn S tile: row stride 2048 floats; bank spread via XOR swizzle of col bits 2..4 by row
#define SWZ(r, c) ((c) ^ (((r) & 7) << 2))

typedef __bf16 bf16_t;
typedef __bf16 bf16x8 __attribute__((ext_vector_type(8)));
typedef __bf16 bf16x4 __attribute__((ext_vector_type(4)));
typedef float f32x4 __attribute__((ext_vector_type(4)));

// float -> bf16 round-to-nearest-even
__device__ __forceinline__ bf16_t f2b(float f) {
    union { float f; unsigned u; } in;
    in.f = f;
    unsigned r = (in.u + 0x7fffu + ((in.u >> 16) & 1u)) >> 16;
    union { unsigned short s; bf16_t b; } out;
    out.s = (unsigned short)r;
    return out.b;
}

// hw packed f32->bf16 RNE (no builtin on gfx950)
__device__ __forceinline__ unsigned cvt_pk_bf16(float lo, float hi) {
    unsigned r;
    asm("v_cvt_pk_bf16_f32 %0, %1, %2" : "=v"(r) : "v"(lo), "v"(hi));
    return r;
}

// async global->LDS, 16B per lane (dest = wave-uniform base + lane*16, linear)
__device__ __forceinline__ void gload_lds16(const bf16_t* g, bf16_t* l) {
    __builtin_amdgcn_global_load_lds((const __attribute__((address_space(1))) void*)g,
                                     (__attribute__((address_space(3))) void*)l, 16, 0, 0);
}

// ---------------- cast fp32 -> bf16 (both tensors in one launch) ----------------
__global__ void cast_f32_bf16_2(const float* __restrict__ a, bf16_t* __restrict__ da,
                                const float* __restrict__ b, bf16_t* __restrict__ db, int n) {
    const float* src = blockIdx.z ? b : a;
    bf16_t* dst = blockIdx.z ? db : da;
    int idx = (blockIdx.x * blockDim.x + threadIdx.x) * 4;
    if (idx + 3 < n) {
        float4 v = *(const float4*)(src + idx);
        bf16x4 o;
        o[0] = f2b(v.x); o[1] = f2b(v.y); o[2] = f2b(v.z); o[3] = f2b(v.w);
        *(bf16x4*)(dst + idx) = o;
    }
}

// ---------------- transpose 1024x1024 fp32 -> bf16, 4 weights in one launch -----------
__global__ void transpose_cast4(const float* __restrict__ s0, const float* __restrict__ s1,
                                const float* __restrict__ s2, const float* __restrict__ s3,
                                bf16_t* __restrict__ d0, bf16_t* __restrict__ d1,
                                bf16_t* __restrict__ d2, bf16_t* __restrict__ d3) {
    const float* src = blockIdx.z == 0 ? s0 : blockIdx.z == 1 ? s1 : blockIdx.z == 2 ? s2 : s3;
    bf16_t* dst = blockIdx.z == 0 ? d0 : blockIdx.z == 1 ? d1 : blockIdx.z == 2 ? d2 : d3;
    __shared__ float tile[32][33];
    int n0 = blockIdx.x * 32, k0 = blockIdx.y * 32;
    int tx = threadIdx.x, ty = threadIdx.y;  // 32 x 8
#pragma unroll
    for (int i = 0; i < 4; i++)
        tile[ty + i * 8][tx] = src[(size_t)(k0 + ty + i * 8) * D_ + n0 + tx];
    __syncthreads();
#pragma unroll
    for (int i = 0; i < 4; i++)
        dst[(size_t)(n0 + ty + i * 8) * D_ + k0 + tx] = f2b(tile[tx][ty + i * 8]);
}

// ---------------- NT GEMM: C[m][n] = sum_k A[m][k]*Bt[n][k]  (64x64 tile, 4 blk/CU) ---
// grid (M/64, N/64). Staging: global_load_lds 16B, linear LDS with XOR chunk swizzle
// (pre-swizzled global source + same XOR on ds_read side; rule: both sides or neither).
// MODE 0: bf16 row-major out, scaled. MODE 1: Vt[((b*16+h)*64+d)*2048+m] via LDS
// transpose. MODE 2: fp32 row-major out.
template <int MODE>
__global__ __launch_bounds__(256, 4) void gemm_nt(const bf16_t* __restrict__ A,
                                                  const bf16_t* __restrict__ Bt,
                                                  void* __restrict__ Cout, float scale) {
    __shared__ __align__(16) bf16_t As[64 * 64];
    __shared__ __align__(16) bf16_t Bs[64 * 64];
    int m0 = blockIdx.x * 64, n0 = blockIdx.y * 64;
    int tid = threadIdx.x;
    int wave = tid >> 6, lane = tid & 63, quad = lane >> 4, l16 = lane & 15;
    int wr = wave >> 1, wc = wave & 1;
    f32x4 acc[2][2] = {};

    // staging: thread -> LDS slot (row tid>>3, 16B-chunk tid&7); source chunk XOR'd
    int srow = tid >> 3, schunk = tid & 7;
    int sw = schunk ^ (srow & 7);
    const bf16_t* ga = &A[(size_t)(m0 + srow) * D_ + sw * 8];
    const bf16_t* gb = &Bt[(size_t)(n0 + srow) * D_ + sw * 8];
    bf16_t* la = &As[tid * 8];
    bf16_t* lb = &Bs[tid * 8];

    for (int k0 = 0; k0 < D_; k0 += 64) {
        gload_lds16(ga + k0, la);
        gload_lds16(ga + k0 + 32 * D_, la + 2048);
        gload_lds16(gb + k0, lb);
        gload_lds16(gb + k0 + 32 * D_, lb + 2048);
        __syncthreads();
        bf16x8 af[2][2], bfr[2][2];
#pragma unroll
        for (int t = 0; t < 2; t++)
#pragma unroll
            for (int ks = 0; ks < 2; ks++) {
                int ca = ((ks * 4 + quad) ^ (l16 & 7)) * 8;  // read-side XOR (involution)
                af[t][ks] = *(bf16x8*)&As[(wr * 32 + t * 16 + l16) * 64 + ca];
                bfr[t][ks] = *(bf16x8*)&Bs[(wc * 32 + t * 16 + l16) * 64 + ca];
            }
#pragma unroll
        for (int i = 0; i < 2; i++)
#pragma unroll
            for (int j = 0; j < 2; j++)
#pragma unroll
                for (int ks = 0; ks < 2; ks++)
                    acc[i][j] = __builtin_amdgcn_mfma_f32_16x16x32_bf16(af[i][ks], bfr[j][ks],
                                                                        acc[i][j], 0, 0, 0);
        __syncthreads();
    }

    if (MODE == 1) {
        // transpose 64x64 tile in LDS, then write 128B-contiguous runs along m
        bf16_t* Ts = As;  // 8 KB
#pragma unroll
        for (int j = 0; j < 2; j++)
#pragma unroll
            for (int i = 0; i < 2; i++)
#pragma unroll
                for (int rp = 0; rp < 2; rp++) {
                    unsigned pk = cvt_pk_bf16(acc[i][j][rp * 2] * scale, acc[i][j][rp * 2 + 1] * scale);
                    *(unsigned*)&Ts[(wc * 32 + j * 16 + l16) * 64 + wr * 32 + i * 16 + quad * 4 + rp * 2] = pk;
                }
        __syncthreads();
        int bb = m0 >> 11, hh = n0 >> 6, mmb = m0 & 2047;  // n0 = 64*head exactly
        bf16_t* dst = (bf16_t*)Cout + (((size_t)(bb * H_ + hh) * Dh_) << 11) + mmb;
#pragma unroll
        for (int it = 0; it < 2; it++) {
            int task = it * 256 + tid;
            int d = task >> 3, ch = task & 7;
            *(bf16x8*)&dst[((size_t)d << 11) + ch * 8] = *(bf16x8*)&Ts[d * 64 + ch * 8];
        }
        return;
    }

#pragma unroll
    for (int i = 0; i < 2; i++)
#pragma unroll
        for (int j = 0; j < 2; j++) {
            int n = n0 + wc * 32 + j * 16 + l16;
#pragma unroll
            for (int r = 0; r < 4; r++) {
                int m = m0 + wr * 32 + i * 16 + quad * 4 + r;
                float v = acc[i][j][r] * scale;
                if (MODE == 0) {
                    ((bf16_t*)Cout)[(size_t)m * D_ + n] = f2b(v);
                } else {
                    ((float*)Cout)[(size_t)m * D_ + n] = v;
                }
            }
        }
}

// ---------------- fused attention: S=QK^T+bias, softmax, write align, PV --------------
// 1024 threads (16 waves); 128 KiB LDS S tile -> 1 block/CU, 4 waves/SIMD.
// 1-D grid with bijective XCD remap: the 128 blocks sharing a (b,h) K/V/bias panel
// land on one XCD's L2 (T1).
__global__ __launch_bounds__(1024) void attn_fused(const bf16_t* __restrict__ Q,
                                                   const bf16_t* __restrict__ K,
                                                   const bf16_t* __restrict__ Vt,
                                                   const float* __restrict__ bias,
                                                   float* __restrict__ align_out,
                                                   bf16_t* __restrict__ AO) {
    extern __shared__ float S[];  // 16 rows x 2048 floats, XOR-swizzled cols
    __shared__ float rowinv[16];
    int p = blockIdx.x;
    int L = (p & 7) * 512 + (p >> 3);  // bijective: consecutive L share one XCD
    int i0 = (L & 127) * 16;
    int h = (L >> 7) & 15;
    int b = L >> 11;
    int tid = threadIdx.x, wave = tid >> 6, lane = tid & 63, quad = lane >> 4, l16 = lane & 15;

    // Q A-fragments (16 rows x Dh=64), shared by all waves
    size_t qrow = (size_t)(b * I_ + i0 + l16) * D_ + h * Dh_ + quad * 8;
    bf16x8 aq0 = *(const bf16x8*)&Q[qrow];
    bf16x8 aq1 = *(const bf16x8*)&Q[qrow + 32];

    // ---- QK^T: each wave does 8 consecutive m-tiles ----
#pragma unroll
    for (int t = 0; t < 8; t++) {
        int m0 = wave * 128 + t * 16;
        size_t krow = (size_t)(b * M_ + m0 + l16) * D_ + h * Dh_ + quad * 8;
        bf16x8 bk0 = *(const bf16x8*)&K[krow];
        bf16x8 bk1 = *(const bf16x8*)&K[krow + 32];
        f32x4 acc = {};
        acc = __builtin_amdgcn_mfma_f32_16x16x32_bf16(aq0, bk0, acc, 0, 0, 0);
        acc = __builtin_amdgcn_mfma_f32_16x16x32_bf16(aq1, bk1, acc, 0, 0, 0);
#pragma unroll
        for (int r = 0; r < 4; r++) {
            int i = quad * 4 + r;
            float v = acc[r] + bias[((size_t)b * I_ + i0 + i) * M_ + m0 + l16];
            S[i * 2048 + SWZ(i, m0 + l16)] = v;
        }
    }
    __syncthreads();

    // ---- softmax stats: one full wave per row, 64-lane shuffle reduce ----
    {
        int row = wave;
        float* srow = &S[row * 2048];
        float mx = -1e30f;
#pragma unroll
        for (int t = 0; t < 8; t++) {
            float4 v = *(float4*)&srow[SWZ(row, lane * 4 + t * 256)];
            mx = fmaxf(mx, fmaxf(fmaxf(v.x, v.y), fmaxf(v.z, v.w)));
        }
#pragma unroll
        for (int off = 1; off < 64; off <<= 1) mx = fmaxf(mx, __shfl_xor(mx, off));
        float sum = 0.f;
#pragma unroll
        for (int t = 0; t < 8; t++) {
            float4 v = *(float4*)&srow[SWZ(row, lane * 4 + t * 256)];
            v.x = __expf(v.x - mx); v.y = __expf(v.y - mx);
            v.z = __expf(v.z - mx); v.w = __expf(v.w - mx);
            *(float4*)&srow[SWZ(row, lane * 4 + t * 256)] = v;
            sum += v.x + v.y + v.z + v.w;
        }
#pragma unroll
        for (int off = 1; off < 64; off <<= 1) sum += __shfl_xor(sum, off);
        if (lane == 0) rowinv[row] = 1.0f / sum;
    }
    __syncthreads();

    // ---- write align block (16 x 2048 fp32, contiguous float4 stores) ----
    {
        float* dst = align_out + (((size_t)(b * H_ + h) * I_ + i0) << 11);
        for (int idx = tid; idx < 16 * 2048 / 4; idx += 1024) {
            int r = idx >> 9;
            int c = (idx & 511) * 4;
            float4 v = *(float4*)&S[r * 2048 + SWZ(r, c)];
            float iv = rowinv[r];
            v.x *= iv; v.y *= iv; v.z *= iv; v.w *= iv;
            *(float4*)&dst[((size_t)r << 11) + c] = v;
        }
    }

    // ---- PV: wave = (ktgroup, colgroup); partial accumulate then LDS reduce ----
    {
        int cg = wave & 3, kg = wave >> 2;
        int n0 = cg * 16;
        f32x4 o0 = {}, o1 = {};
        const bf16_t* vrow = &Vt[((size_t)(b * H_ + h) * Dh_ + n0 + l16) << 11];
        const float* srow = &S[l16 * 2048];
#pragma unroll
        for (int t = 0; t < 8; t++) {
            int kt = kg * 512 + t * 64;
            int c0 = kt + quad * 8;
            float4 f0 = *(const float4*)&srow[SWZ(l16, c0)];
            float4 f1 = *(const float4*)&srow[SWZ(l16, c0 + 4)];
            float4 f2 = *(const float4*)&srow[SWZ(l16, c0 + 32)];
            float4 f3 = *(const float4*)&srow[SWZ(l16, c0 + 36)];
            union { bf16x8 v; unsigned u[4]; } a0, a1;
            a0.u[0] = cvt_pk_bf16(f0.x, f0.y); a0.u[1] = cvt_pk_bf16(f0.z, f0.w);
            a0.u[2] = cvt_pk_bf16(f1.x, f1.y); a0.u[3] = cvt_pk_bf16(f1.z, f1.w);
            a1.u[0] = cvt_pk_bf16(f2.x, f2.y); a1.u[1] = cvt_pk_bf16(f2.z, f2.w);
            a1.u[2] = cvt_pk_bf16(f3.x, f3.y); a1.u[3] = cvt_pk_bf16(f3.z, f3.w);
            bf16x8 v0 = *(const bf16x8*)&vrow[kt + quad * 8];
            bf16x8 v1 = *(const bf16x8*)&vrow[kt + 32 + quad * 8];
            o0 = __builtin_amdgcn_mfma_f32_16x16x32_bf16(a0.v, v0, o0, 0, 0, 0);
            o1 = __builtin_amdgcn_mfma_f32_16x16x32_bf16(a1.v, v1, o1, 0, 0, 0);
        }
        __syncthreads();  // all reads of S complete; safe to reuse S as scratch
        float* scr = &S[(size_t)wave * 512 + (size_t)lane * 8];
        *(f32x4*)scr = o0;
        *(f32x4*)(scr + 4) = o1;
        __syncthreads();
        if (kg == 0) {
#pragma unroll
            for (int w2 = 1; w2 < 4; w2++) {
                const float* pp = &S[(size_t)(w2 * 4 + cg) * 512 + (size_t)lane * 8];
                f32x4 p0 = *(const f32x4*)pp;
                f32x4 p1 = *(const f32x4*)(pp + 4);
                o0 += p0;
                o1 += p1;
            }
#pragma unroll
            for (int r = 0; r < 4; r++) {
                int i = quad * 4 + r;
                float v = (o0[r] + o1[r]) * rowinv[i];
                AO[(size_t)(b * I_ + i0 + i) * D_ + h * Dh_ + n0 + l16] = f2b(v);
            }
        }
    }
}

extern "C" void kernel_launch(void* const* d_in, const int* in_sizes, int n_in,
                              void* d_out, int out_size, void* d_ws, size_t ws_size,
                              hipStream_t stream) {
    const float* input  = (const float*)d_in[0];
    const float* memory = (const float*)d_in[1];
    const float* bias   = (const float*)d_in[2];
    const float* Wq     = (const float*)d_in[3];
    const float* Wk     = (const float*)d_in[4];
    const float* Wv     = (const float*)d_in[5];
    const float* Wo     = (const float*)d_in[6];

    float* out   = (float*)d_out;
    float* align = out + (size_t)B_ * I_ * D_;

    char* ws = (char*)d_ws;
    const size_t nBID = (size_t)B_ * I_ * D_;   // 4,194,304
    const size_t nDD  = (size_t)D_ * D_;        // 1,048,576
    bf16_t* in_b  = (bf16_t*)ws; ws += nBID * 2;
    bf16_t* mem_b = (bf16_t*)ws; ws += nBID * 2;
    bf16_t* Wq_t  = (bf16_t*)ws; ws += nDD * 2;
    bf16_t* Wk_t  = (bf16_t*)ws; ws += nDD * 2;
    bf16_t* Wv_t  = (bf16_t*)ws; ws += nDD * 2;
    bf16_t* Wo_t  = (bf16_t*)ws; ws += nDD * 2;
    bf16_t* Qb    = (bf16_t*)ws; ws += nBID * 2;
    bf16_t* Kb    = (bf16_t*)ws; ws += nBID * 2;
    bf16_t* Vt    = (bf16_t*)ws; ws += nBID * 2;
    bf16_t* AO    = (bf16_t*)ws; ws += nBID * 2;

    // casts (both tensors, one launch)
    cast_f32_bf16_2<<<dim3(nBID / 1024, 1, 2), 256, 0, stream>>>(input, in_b, memory, mem_b, (int)nBID);
    // weight transposes (all four, one launch)
    transpose_cast4<<<dim3(32, 32, 4), dim3(32, 8), 0, stream>>>(Wq, Wk, Wv, Wo, Wq_t, Wk_t, Wv_t, Wo_t);

    // projections: [4096,1024] @ [1024,1024]^T-layout, 64x64 tiles -> 1024 blocks (4/CU)
    dim3 gg(64, 16);
    gemm_nt<0><<<gg, 256, 0, stream>>>(in_b, Wq_t, Qb, 0.125f);   // Dh^-0.5 folded
    gemm_nt<0><<<gg, 256, 0, stream>>>(mem_b, Wk_t, Kb, 1.0f);
    gemm_nt<1><<<gg, 256, 0, stream>>>(mem_b, Wv_t, Vt, 1.0f);    // per-head transposed

    // fused attention: 1-D grid 4096, XCD-remapped inside
    attn_fused<<<dim3(4096), 1024, 16 * 2048 * 4, stream>>>(Qb, Kb, Vt, bias, align, AO);

    // output projection (fp32 out)
    gemm_nt<2><<<gg, 256, 0, stream>>>(AO, Wo_t, out, 1.0f);
}